// Round 7
// baseline (273.201 us; speedup 1.0000x reference)
//
#include <hip/hip_runtime.h>
#include <stdint.h>

typedef unsigned short u16;
typedef unsigned int u32;
typedef __attribute__((ext_vector_type(8))) short short8;
typedef __attribute__((ext_vector_type(4))) float floatx4;

__device__ __forceinline__ u16 f2b(float f) {
  union { float f; u32 u; } c; c.f = f;
  u32 u = c.u;
  u += 0x7fffu + ((u >> 16) & 1u);
  return (u16)(u >> 16);
}
__device__ __forceinline__ float b2f(u16 h) {
  union { u32 u; float f; } c; c.u = ((u32)h) << 16;
  return c.f;
}

// ---------------- mega-prep: argmin parts | transposes | weight casts | zero sums ----------------
// blocks [0,512): argmin  [512,2560): f1 transpose  [2560,3584): f2 transpose  [3584,4224): casts+zero
__global__ void prep_all_k(const float* __restrict__ xyz1, const float* __restrict__ xyz2,
                           float2* __restrict__ cand,
                           const float* __restrict__ f1, u16* __restrict__ f1t,
                           const float* __restrict__ f2, u16* __restrict__ f2t,
                           const float* __restrict__ w0, u16* __restrict__ w0b,
                           const float* __restrict__ w1, u16* __restrict__ w1b,
                           float* __restrict__ sums) {
  __shared__ __align__(16) char smem[9216];
  int blk = blockIdx.x, t = threadIdx.x;
  if (blk < 512) {
    // ---- argmin: 4 query points/thread, one 256-chunk of M ----
    float4* s2 = (float4*)smem;
    int nq = blk & 7, mq = (blk >> 3) & 7, b = blk >> 6;
    const float* x2 = xyz2 + ((size_t)b * 2048 + mq * 256) * 3;
    s2[t] = make_float4(x2[t * 3], x2[t * 3 + 1], x2[t * 3 + 2], 0.f);
    __syncthreads();
    int n0 = nq * 1024 + t;
    float px[4], py[4], pz[4];
#pragma unroll
    for (int q = 0; q < 4; q++) {
      const float* p1 = xyz1 + ((size_t)b * 8192 + n0 + q * 256) * 3;
      px[q] = p1[0]; py[q] = p1[1]; pz[q] = p1[2];
    }
    float best[4] = {3.0e38f, 3.0e38f, 3.0e38f, 3.0e38f};
    int bi[4] = {0, 0, 0, 0};
#pragma unroll 4
    for (int m = 0; m < 256; m++) {
      float4 qq = s2[m];
#pragma unroll
      for (int q = 0; q < 4; q++) {
        float dx = px[q] - qq.x, dy = py[q] - qq.y, dz = pz[q] - qq.z;
        float d = fmaf(dz, dz, fmaf(dy, dy, dx * dx));  // EXACT contraction from passing rounds
        bool c = d < best[q];
        best[q] = c ? d : best[q];
        bi[q] = c ? m : bi[q];
      }
    }
#pragma unroll
    for (int q = 0; q < 4; q++) {
      int n = n0 + q * 256;
      cand[(size_t)mq * 65536 + (size_t)b * 8192 + n] =
          make_float2(best[q], __int_as_float(mq * 256 + bi[q]));
    }
  } else if (blk < 3584) {
    // ---- tiled transpose+cast [B][C][N] fp32 -> [B][N][C] bf16 ----
    const float* in; u16* out; int C, N, bx, by, bz;
    if (blk < 2560) { int rel = blk - 512;  in = f1; out = f1t; C = 128; N = 8192; bx = rel & 127; by = (rel >> 7) & 1; bz = rel >> 8; }
    else            { int rel = blk - 2560; in = f2; out = f2t; C = 256; N = 2048; bx = rel & 31;  by = (rel >> 5) & 3; bz = rel >> 7; }
    u16 (*tile)[72] = (u16(*)[72])smem;
    int c0 = by * 64, n0 = bx * 64;
    const float* src = in + ((size_t)bz * C + c0) * N + n0;
#pragma unroll
    for (int i = 0; i < 4; i++) {
      int id = t + i * 256;
      int c = id >> 4, nq = (id & 15) * 4;
      float4 v = *(const float4*)(src + (size_t)c * N + nq);
      tile[nq + 0][c] = f2b(v.x);
      tile[nq + 1][c] = f2b(v.y);
      tile[nq + 2][c] = f2b(v.z);
      tile[nq + 3][c] = f2b(v.w);
    }
    __syncthreads();
    int n = t >> 2, ch = (t & 3) * 16;
    u16* dst = out + ((size_t)bz * N + n0 + n) * C + c0 + ch;
    *(uint4*)dst = *(const uint4*)&tile[n][ch];
    *(uint4*)(dst + 8) = *(const uint4*)&tile[n][ch + 8];
  } else {
    // ---- weight casts + zero stats ----
    int rel = blk - 3584;
    int i = rel * 256 + t;
    if (rel < 384) w0b[i] = f2b(w0[i]);
    else { int j = i - 98304; w1b[j] = f2b(w1[j]); }
    if (rel < 4) sums[i] = 0.f;
  }
}

// ---------------- GEMM1: 256o x 64p blocks, B-tile in LDS (full K), A streamed from L2 ----------------
// No in-loop barriers: K-loop is global_load(A-frag) + ds_read(B-frag) + MFMA only.
__global__ __launch_bounds__(256, 3) void gemm1_k(const u16* __restrict__ w0b, const u16* __restrict__ f1t,
                                                  const u16* __restrict__ f2t, const float2* __restrict__ cand,
                                                  float* __restrict__ sum0, float* __restrict__ sq0,
                                                  u16* __restrict__ y0) {
  __shared__ __align__(16) u16 Bs[64 * 392];  // 64 pts x 384 k, row pad 392 (word stride 196 = 4 mod 32)
  __shared__ int sidx[64];
  int t = threadIdx.x;
  int pt0 = blockIdx.x * 64;
  int b = pt0 >> 13;
  if (t < 64) {  // fused argmin combine over the 8 m-chunks
    int p = pt0 + t;
    float bd = 3.0e38f; int bi = 0;
#pragma unroll
    for (int qc = 0; qc < 8; qc++) {
      float2 c = cand[(size_t)qc * 65536 + p];
      if (c.x < bd) { bd = c.x; bi = __float_as_int(c.y); }  // strict <: lower chunk wins ties
    }
    sidx[t] = bi;
  }
  __syncthreads();
  // stage B once: f1 channels (k<128): 64 pts * 128 ch = 1024 uint4
#pragma unroll
  for (int i = 0; i < 4; i++) {
    int id = i * 256 + t;
    int p = id >> 4, kc = (id & 15) * 8;
    uint4 v = *(const uint4*)(f1t + (size_t)(pt0 + p) * 128 + kc);
    *(uint4*)&Bs[p * 392 + kc] = v;
  }
  // gathered f2 channels (k in [128,384)): 64 pts * 256 ch = 2048 uint4
#pragma unroll
  for (int i = 0; i < 8; i++) {
    int id = i * 256 + t;
    int p = id >> 5, kc = (id & 31) * 8;
    uint4 v = *(const uint4*)(f2t + ((size_t)(b << 11) + sidx[p]) * 256 + kc);
    *(uint4*)&Bs[p * 392 + 128 + kc] = v;
  }
  __syncthreads();  // the ONLY compute barrier

  int lane = t & 63, wave = t >> 6;
  int wrow = wave * 64;                 // this wave's 64 output channels
  int lr = lane & 15, lq = lane >> 4;
  const u16* ab = w0b + (size_t)(wrow + lr) * 384 + lq * 8;  // A frags: imm offsets for i,k
  const u16* bb = &Bs[lr * 392 + lq * 8];
  floatx4 zero = {0.f, 0.f, 0.f, 0.f};
  floatx4 acc[4][4];
#pragma unroll
  for (int i = 0; i < 4; i++)
#pragma unroll
    for (int j = 0; j < 4; j++) acc[i][j] = zero;

#pragma unroll
  for (int k0 = 0; k0 < 384; k0 += 32) {
    short8 af[4], bf[4];
#pragma unroll
    for (int i = 0; i < 4; i++) af[i] = *(const short8*)(ab + (size_t)i * 16 * 384 + k0);
#pragma unroll
    for (int j = 0; j < 4; j++) bf[j] = *(const short8*)(bb + j * 16 * 392 + k0);
#pragma unroll
    for (int i = 0; i < 4; i++)
#pragma unroll
      for (int j = 0; j < 4; j++)
        acc[i][j] = __builtin_amdgcn_mfma_f32_16x16x32_bf16(af[i], bf[j], acc[i][j], 0, 0, 0);
  }
  // y0 stores: block covers all 256 o for 64 p -> full 512B rows, clean write coalescing
#pragma unroll
  for (int i = 0; i < 4; i++) {
#pragma unroll
    for (int j = 0; j < 4; j++) {
      int o = wrow + i * 16 + lq * 4;
      int p = pt0 + j * 16 + lr;
      uint2 pk;
      pk.x = (u32)f2b(acc[i][j][0]) | ((u32)f2b(acc[i][j][1]) << 16);
      pk.y = (u32)f2b(acc[i][j][2]) | ((u32)f2b(acc[i][j][3]) << 16);
      *(uint2*)&y0[(size_t)p * 256 + o] = pk;
    }
  }
  // fused stats0 from fp32 accs (sum over j in-register, over lr by shfl, cross-wave via LDS)
  __syncthreads();
  float* red = (float*)Bs;
  red[t] = 0.f; red[t + 256] = 0.f;
  __syncthreads();
#pragma unroll
  for (int i = 0; i < 4; i++) {
#pragma unroll
    for (int r = 0; r < 4; r++) {
      float s = acc[i][0][r] + acc[i][1][r] + acc[i][2][r] + acc[i][3][r];
      float q = acc[i][0][r] * acc[i][0][r] + acc[i][1][r] * acc[i][1][r] +
                acc[i][2][r] * acc[i][2][r] + acc[i][3][r] * acc[i][3][r];
#pragma unroll
      for (int m = 8; m >= 1; m >>= 1) { s += __shfl_xor(s, m); q += __shfl_xor(q, m); }
      if (lr == 0) {
        int o = wrow + i * 16 + lq * 4 + r;
        atomicAdd(&red[o], s);
        atomicAdd(&red[256 + o], q);
      }
    }
  }
  __syncthreads();
  atomicAdd(&sum0[t], red[t]);
  atomicAdd(&sq0[t], red[256 + t]);
}

// ---------------- GEMM2: 256o x 64p blocks, BN0+ReLU fused into the one-time B staging ----------------
__global__ __launch_bounds__(256, 3) void gemm2_k(const u16* __restrict__ w1b, const u16* __restrict__ y0,
                                                  const float* __restrict__ sum0, const float* __restrict__ sq0,
                                                  const float* __restrict__ gamma0, const float* __restrict__ beta0,
                                                  float* __restrict__ sum1, float* __restrict__ sq1,
                                                  u16* __restrict__ y1) {
  __shared__ __align__(16) u16 Bs[64 * 264];  // 64 pts x 256 k, row pad 264 (word stride 132 = 4 mod 32)
  __shared__ float ssc[256], ssh[256];
  int t = threadIdx.x;
  {  // fused bnparam0
    float mean = sum0[t] * (1.f / 65536.f);
    float var = fmaxf(sq0[t] * (1.f / 65536.f) - mean * mean, 0.f);
    float r = rsqrtf(var + 1e-5f);
    float sc = gamma0[t] * r;
    ssc[t] = sc;
    ssh[t] = beta0[t] - mean * sc;
  }
  int pt0 = blockIdx.x * 64;
  __syncthreads();
  // stage B once with BN0+ReLU applied: 64 pts * 256 ch = 2048 uint4
#pragma unroll
  for (int i = 0; i < 8; i++) {
    int id = i * 256 + t;
    int p = id >> 5, kc = (id & 31) * 8;
    uint4 raw = *(const uint4*)(y0 + (size_t)(pt0 + p) * 256 + kc);
    float4 sc0 = *(const float4*)&ssc[kc], sc1 = *(const float4*)&ssc[kc + 4];
    float4 sh0 = *(const float4*)&ssh[kc], sh1 = *(const float4*)&ssh[kc + 4];
    u32 rw[4] = {raw.x, raw.y, raw.z, raw.w};
    float scs[8] = {sc0.x, sc0.y, sc0.z, sc0.w, sc1.x, sc1.y, sc1.z, sc1.w};
    float shs[8] = {sh0.x, sh0.y, sh0.z, sh0.w, sh1.x, sh1.y, sh1.z, sh1.w};
    u32 ow[4];
#pragma unroll
    for (int w = 0; w < 4; w++) {
      float v0 = fmaxf(b2f((u16)(rw[w] & 0xffffu)) * scs[w * 2] + shs[w * 2], 0.f);
      float v1 = fmaxf(b2f((u16)(rw[w] >> 16)) * scs[w * 2 + 1] + shs[w * 2 + 1], 0.f);
      ow[w] = (u32)f2b(v0) | ((u32)f2b(v1) << 16);
    }
    uint4 ov; ov.x = ow[0]; ov.y = ow[1]; ov.z = ow[2]; ov.w = ow[3];
    *(uint4*)&Bs[p * 264 + kc] = ov;
  }
  __syncthreads();  // the ONLY compute barrier

  int lane = t & 63, wave = t >> 6;
  int wrow = wave * 64;
  int lr = lane & 15, lq = lane >> 4;
  const u16* ab = w1b + (size_t)(wrow + lr) * 256 + lq * 8;
  const u16* bb = &Bs[lr * 264 + lq * 8];
  floatx4 zero = {0.f, 0.f, 0.f, 0.f};
  floatx4 acc[4][4];
#pragma unroll
  for (int i = 0; i < 4; i++)
#pragma unroll
    for (int j = 0; j < 4; j++) acc[i][j] = zero;

#pragma unroll
  for (int k0 = 0; k0 < 256; k0 += 32) {
    short8 af[4], bf[4];
#pragma unroll
    for (int i = 0; i < 4; i++) af[i] = *(const short8*)(ab + (size_t)i * 16 * 256 + k0);
#pragma unroll
    for (int j = 0; j < 4; j++) bf[j] = *(const short8*)(bb + j * 16 * 264 + k0);
#pragma unroll
    for (int i = 0; i < 4; i++)
#pragma unroll
      for (int j = 0; j < 4; j++)
        acc[i][j] = __builtin_amdgcn_mfma_f32_16x16x32_bf16(af[i], bf[j], acc[i][j], 0, 0, 0);
  }
#pragma unroll
  for (int i = 0; i < 4; i++) {
#pragma unroll
    for (int j = 0; j < 4; j++) {
      int o = wrow + i * 16 + lq * 4;
      int p = pt0 + j * 16 + lr;
      uint2 pk;
      pk.x = (u32)f2b(acc[i][j][0]) | ((u32)f2b(acc[i][j][1]) << 16);
      pk.y = (u32)f2b(acc[i][j][2]) | ((u32)f2b(acc[i][j][3]) << 16);
      *(uint2*)&y1[(size_t)p * 256 + o] = pk;
    }
  }
  // fused stats1
  __syncthreads();
  float* red = (float*)Bs;
  red[t] = 0.f; red[t + 256] = 0.f;
  __syncthreads();
#pragma unroll
  for (int i = 0; i < 4; i++) {
#pragma unroll
    for (int r = 0; r < 4; r++) {
      float s = acc[i][0][r] + acc[i][1][r] + acc[i][2][r] + acc[i][3][r];
      float q = acc[i][0][r] * acc[i][0][r] + acc[i][1][r] * acc[i][1][r] +
                acc[i][2][r] * acc[i][2][r] + acc[i][3][r] * acc[i][3][r];
#pragma unroll
      for (int m = 8; m >= 1; m >>= 1) { s += __shfl_xor(s, m); q += __shfl_xor(q, m); }
      if (lr == 0) {
        int o = wrow + i * 16 + lq * 4 + r;
        atomicAdd(&red[o], s);
        atomicAdd(&red[256 + o], q);
      }
    }
  }
  __syncthreads();
  atomicAdd(&sum1[t], red[t]);
  atomicAdd(&sq1[t], red[256 + t]);
}

// ---------------- finalize: fused BN1 params + BN1+ReLU + transpose -> [b][o][n] fp32 ----------------
__global__ void finalize_k(const u16* __restrict__ y1, const float* __restrict__ sum1,
                           const float* __restrict__ sq1, const float* __restrict__ gamma1,
                           const float* __restrict__ beta1, float* __restrict__ out) {
  __shared__ float tile[64][65];
  __shared__ float fs[64], fh[64];
  int b = blockIdx.z, o0 = blockIdx.y * 64, n0 = blockIdx.x * 64;
  int t = threadIdx.x;
  if (t < 64) {
    int o = o0 + t;
    float mean = sum1[o] * (1.f / 65536.f);
    float var = fmaxf(sq1[o] * (1.f / 65536.f) - mean * mean, 0.f);
    float r = rsqrtf(var + 1e-5f);
    float sc = gamma1[o] * r;
    fs[t] = sc;
    fh[t] = beta1[o] - mean * sc;
  }
  __syncthreads();
  int pl = t >> 2, ch = (t & 3) * 16;
  const u16* src = y1 + ((size_t)(b * 8192 + n0 + pl)) * 256 + o0 + ch;
  uint4 r0 = *(const uint4*)src;
  uint4 r1 = *(const uint4*)(src + 8);
  u16 hv[16];
  *(uint4*)&hv[0] = r0;
  *(uint4*)&hv[8] = r1;
#pragma unroll
  for (int e = 0; e < 16; e++) {
    float v = b2f(hv[e]) * fs[ch + e] + fh[ch + e];
    tile[pl][ch + e] = fmaxf(v, 0.f);
  }
  __syncthreads();
  int ol = t >> 2, nch = (t & 3) * 16;
  float* dst = out + ((size_t)(b * 256 + o0 + ol)) * 8192 + n0 + nch;
#pragma unroll
  for (int j = 0; j < 16; j += 4) {
    float4 v = make_float4(tile[nch + j][ol], tile[nch + j + 1][ol],
                           tile[nch + j + 2][ol], tile[nch + j + 3][ol]);
    *(float4*)(dst + j) = v;
  }
}

extern "C" void kernel_launch(void* const* d_in, const int* in_sizes, int n_in,
                              void* d_out, int out_size, void* d_ws, size_t ws_size,
                              hipStream_t stream) {
  const float* xyz1      = (const float*)d_in[0];
  const float* xyz2      = (const float*)d_in[1];
  const float* features1 = (const float*)d_in[2];
  const float* features2 = (const float*)d_in[3];
  const float* conv_w0   = (const float*)d_in[4];
  const float* gamma0    = (const float*)d_in[5];
  const float* beta0     = (const float*)d_in[6];
  const float* conv_w1   = (const float*)d_in[7];
  const float* gamma1    = (const float*)d_in[8];
  const float* beta1     = (const float*)d_in[9];
  float* out = (float*)d_out;

  char* ws = (char*)d_ws;
  size_t off = 0;
  auto alloc = [&](size_t bytes) {
    char* p = ws + off;
    off = (off + bytes + 4095) & ~(size_t)4095;
    return p;
  };
  float*  sums = (float*)alloc(4 * 256 * 4);            // sum0, sq0, sum1, sq1
  u16*    w0b  = (u16*)alloc(256 * 384 * 2);
  u16*    w1b  = (u16*)alloc(256 * 256 * 2);
  float2* cand = (float2*)alloc((size_t)8 * 65536 * 8); // 4MB
  u16*    f1t  = (u16*)alloc((size_t)65536 * 128 * 2);
  u16*    f2t  = (u16*)alloc((size_t)16384 * 256 * 2);
  u16*    y0   = (u16*)alloc((size_t)65536 * 256 * 2);
  u16*    y1   = (u16*)alloc((size_t)65536 * 256 * 2);

  prep_all_k<<<dim3(4224), 256, 0, stream>>>(xyz1, xyz2, cand, features1, f1t,
                                             features2, f2t, conv_w0, w0b, conv_w1, w1b, sums);
  gemm1_k<<<dim3(1024), 256, 0, stream>>>(w0b, f1t, f2t, cand, sums + 0, sums + 256, y0);
  gemm2_k<<<dim3(1024), 256, 0, stream>>>(w1b, y0, sums + 0, sums + 256, gamma0, beta0,
                                          sums + 512, sums + 768, y1);
  finalize_k<<<dim3(128, 4, 8), 256, 0, stream>>>(y1, sums + 512, sums + 768, gamma1, beta1, out);
}